// Round 3
// baseline (1449.961 us; speedup 1.0000x reference)
//
#include <hip/hip_runtime.h>
#include <hip/hip_bf16.h>

// B=256, I=512, R=1024, L=2, U=11 (step 10's compute is dead; only 10 steps run).
#define B_N 256
#define R_N 1024
#define U_N 11
#define BK 32
#define SP 40   // LDS row stride in bf16 elems (BK+8): 80B rows, 16B-aligned frags

typedef __attribute__((ext_vector_type(8))) short bf16x8;
typedef __attribute__((ext_vector_type(4))) float f32x4;

__device__ __forceinline__ float sigmoid_f(float x) {
    return 1.0f / (1.0f + __expf(-x));
}

__device__ __forceinline__ float tanh_f(float x) {
    x = fminf(15.0f, fmaxf(-15.0f, x));
    const float e = __expf(2.0f * x);
    return (e - 1.0f) / (e + 1.0f);
}

__device__ __forceinline__ short bf16_of(float x) {
    union { __hip_bfloat16 h; short s; } u;
    u.h = __float2bfloat16(x);
    return u.s;
}

__device__ __forceinline__ short4 pack4(float4 v) {
    short4 r;
    r.x = bf16_of(v.x); r.y = bf16_of(v.y);
    r.z = bf16_of(v.z); r.w = bf16_of(v.w);
    return r;
}

// One LSTM layer: pre = A1 @ W1^T + A2 @ W2^T + bi + bh -> cell -> h_out, c_state.
// Block: 512 threads = 8 waves = (2 K-groups) x (4 gates).
// Block tile: M=32 rows x r=16 columns x 4 gates. Grid (R/16=64, B/32=8) = 512
// blocks -> 2 blocks/CU (30.7 KB LDS, launch_bounds(512,4)). Latency hiding via
// cross-block TLP: while one block drains its barrier, the co-resident block
// issues loads/MFMAs. K-loop: double-buffered LDS, ONE __syncthreads per chunk
// (single-barrier dbuf is safe: reads of buf b at chunk c drain at sync(c+1);
// next write of buf b is at chunk c+2, after that common barrier).
__global__ __launch_bounds__(512, 4) void lstm_layer(
    const float* __restrict__ A1, int lda1, int K1, const float* __restrict__ W1,
    const float* __restrict__ A2, int lda2, int K2, const float* __restrict__ W2,
    const float* __restrict__ bi, const float* __restrict__ bh,
    float* __restrict__ c_state,
    float* __restrict__ h_out, int ldh)
{
    // Staging (double-buffered) aliased with sPre (used only after the K-loop).
    //   sA: [buf][group][32*SP]  shorts -> 4 * 2560 B = 10240 B   (offs 0)
    //   sW: [buf][group][64*SP]  shorts -> 4 * 5120 B = 20480 B   (offs 10240)
    //   sPre: float[2][4*32*16] = 16384 B (aliases the above, post-loop only)
    __shared__ __align__(16) char smem_raw[30720];

    const int tid  = threadIdx.x;
    const int lane = tid & 63;
    const int wave = tid >> 6;
    const int group = wave >> 2;      // K-half
    const int gate  = wave & 3;
    const int ln   = lane & 15;
    const int quad = lane >> 4;
    const int lk   = quad * 8;        // k offset within chunk (bf16 elems)
    const int tg   = tid & 255;       // thread index within its K-group

    const int m_base = blockIdx.y * 32;
    const int rb     = blockIdx.x * 16;

    const int Ktot  = K1 + K2;
    const int Khalf = Ktot >> 1;
    const int NC    = Khalf / BK;     // 24 (layer0) or 32 (layer1) -- even

    // Staging coords (per-thread, constant across chunks)
    const int arow = tg >> 3;          // 0..31
    const int acol = (tg & 7) * 4;     // 0,4,..,28

    // Hoisted per-thread base pointers (kc is the only per-chunk variable).
    const float* baseA1 = A1 + (size_t)(m_base + arow) * lda1 + acol;
    const float* baseA2 = A2 + (size_t)(m_base + arow) * lda2 + acol;
    const float* baseW1[2];
    const float* baseW2[2];
#pragma unroll
    for (int l = 0; l < 2; ++l) {
        const int wrow = l * 32 + (tg >> 3);   // 0..63 = gate*16 + rr
        const int g = wrow >> 4, rr = wrow & 15;
        baseW1[l] = W1 + (size_t)(g * R_N + rb + rr) * K1 + acol;
        baseW2[l] = W2 + (size_t)(g * R_N + rb + rr) * K2 + acol;
    }

    f32x4 acc[2];
#pragma unroll
    for (int mf = 0; mf < 2; ++mf) {
        f32x4 z = {0.0f, 0.0f, 0.0f, 0.0f};
        acc[mf] = z;
    }

    // ---- chunk loader: global -> registers (coalesced: 8 lanes cover 128B row seg)
    float4 pA;
    float4 pW[2];
    auto load_chunk = [&](int c) {
        const int kv = group * Khalf + c * BK;
        if (kv < K1) {
            pA = *reinterpret_cast<const float4*>(baseA1 + kv);
#pragma unroll
            for (int l = 0; l < 2; ++l)
                pW[l] = *reinterpret_cast<const float4*>(baseW1[l] + kv);
        } else {
            const int kc = kv - K1;
            pA = *reinterpret_cast<const float4*>(baseA2 + kc);
#pragma unroll
            for (int l = 0; l < 2; ++l)
                pW[l] = *reinterpret_cast<const float4*>(baseW2[l] + kc);
        }
    };

    // ---- one chunk: store regs -> LDS buf, sync, prefetch c+1, read frags, MFMA
    auto body = [&](int c, int buf) {
        short* sAb = reinterpret_cast<short*>(&smem_raw[(size_t)(buf * 2 + group) * 2560]);
        short* sWb = reinterpret_cast<short*>(&smem_raw[10240 + (size_t)(buf * 2 + group) * 5120]);

        *reinterpret_cast<short4*>(&sAb[arow * SP + acol]) = pack4(pA);
#pragma unroll
        for (int l = 0; l < 2; ++l) {
            const int wrow = l * 32 + (tg >> 3);
            *reinterpret_cast<short4*>(&sWb[wrow * SP + acol]) = pack4(pW[l]);
        }

        __syncthreads();                      // staging visible; prior buf reads drained

        if (c + 1 < NC) load_chunk(c + 1);    // issue early: overlaps reads+MFMA below

        bf16x8 af[2], wf;
#pragma unroll
        for (int mf = 0; mf < 2; ++mf)
            af[mf] = *reinterpret_cast<const bf16x8*>(&sAb[(mf * 16 + ln) * SP + lk]);
        wf = *reinterpret_cast<const bf16x8*>(&sWb[(gate * 16 + ln) * SP + lk]);

        acc[0] = __builtin_amdgcn_mfma_f32_16x16x32_bf16(af[0], wf, acc[0], 0, 0, 0);
        acc[1] = __builtin_amdgcn_mfma_f32_16x16x32_bf16(af[1], wf, acc[1], 0, 0, 0);
    };

    load_chunk(0);
#pragma unroll 1
    for (int c = 0; c < NC; c += 2) {
        body(c, 0);
        body(c + 1, 1);
    }

    // ---- merge K-halves + cell (sPre aliases staging; barrier first so all
    //      waves' last-chunk ds_reads are complete before overwrite)
    __syncthreads();
    float* sPre = reinterpret_cast<float*>(smem_raw);   // [group][(gate*32+m)*16 + r]

    // C/D layout: col(r) = lane&15, row(m) = quad*4 + t.
#pragma unroll
    for (int mf = 0; mf < 2; ++mf)
#pragma unroll
        for (int t = 0; t < 4; ++t) {
            const int m = mf * 16 + quad * 4 + t;
            sPre[group * 2048 + (gate * 32 + m) * 16 + ln] = acc[mf][t];
        }
    __syncthreads();

    {
        const int m = tid >> 4;            // 0..31
        const int r = tid & 15;            // 0..15
        const int gm = m_base + m;
        const int gr = rb + r;
        const float pI = sPre[(0 * 32 + m) * 16 + r] + sPre[2048 + (0 * 32 + m) * 16 + r]
                       + bi[0 * R_N + gr] + bh[0 * R_N + gr];
        const float pF = sPre[(1 * 32 + m) * 16 + r] + sPre[2048 + (1 * 32 + m) * 16 + r]
                       + bi[1 * R_N + gr] + bh[1 * R_N + gr];
        const float pO = sPre[(2 * 32 + m) * 16 + r] + sPre[2048 + (2 * 32 + m) * 16 + r]
                       + bi[2 * R_N + gr] + bh[2 * R_N + gr];
        const float pG = sPre[(3 * 32 + m) * 16 + r] + sPre[2048 + (3 * 32 + m) * 16 + r]
                       + bi[3 * R_N + gr] + bh[3 * R_N + gr];
        const size_t cidx = (size_t)gm * R_N + gr;
        const float cv = sigmoid_f(pF) * c_state[cidx] + sigmoid_f(pI) * tanh_f(pG);
        c_state[cidx] = cv;
        h_out[(size_t)gm * ldh + gr] = sigmoid_f(pO) * tanh_f(cv);
    }
}

// Unpack init_states_input (B, 4, R) -> h0 ws, c0 ws, out slot 0 (h1), c1 ws.
__global__ __launch_bounds__(256) void init_states(
    const float* __restrict__ st, float* __restrict__ h0,
    float* __restrict__ c0, float* __restrict__ c1, float* __restrict__ out)
{
    const int idx = blockIdx.x * 256 + threadIdx.x;  // 0 .. 256*1024-1
    const int b = idx >> 10;
    const int r = idx & 1023;
    const float* s = st + (size_t)b * 4096;
    h0[idx] = s[r];
    c0[idx] = s[1024 + r];
    out[(size_t)b * (U_N * R_N) + r] = s[2048 + r];
    c1[idx] = s[3072 + r];
}

extern "C" void kernel_launch(void* const* d_in, const int* in_sizes, int n_in,
                              void* d_out, int out_size, void* d_ws, size_t ws_size,
                              hipStream_t stream)
{
    const float* x   = (const float*)d_in[0];
    const float* st  = (const float*)d_in[1];
    const float* Wi0 = (const float*)d_in[2];
    const float* bi0 = (const float*)d_in[3];
    const float* Wh0 = (const float*)d_in[4];
    const float* bh0 = (const float*)d_in[5];
    const float* Wi1 = (const float*)d_in[6];
    const float* bi1 = (const float*)d_in[7];
    const float* Wh1 = (const float*)d_in[8];
    const float* bh1 = (const float*)d_in[9];
    float* out = (float*)d_out;

    float* h0a = (float*)d_ws;
    float* h0b = h0a + B_N * R_N;
    float* c0  = h0b + B_N * R_N;
    float* c1  = c0 + B_N * R_N;

    init_states<<<dim3((B_N * R_N) / 256), 256, 0, stream>>>(st, h0a, c0, c1, out);

    const dim3 grid(R_N / 16, B_N / 32);  // (64, 8) = 512 blocks, 2 per CU
    for (int u = 0; u < 10; ++u) {
        const float* h0_in = (u & 1) ? h0b : h0a;
        float* h0_out      = (u & 1) ? h0a : h0b;
        // Layer 0: pre0 = x @ Wi0[u]^T + h0 @ Wh0[u]^T + biases
        lstm_layer<<<grid, 512, 0, stream>>>(
            x, 512, 512, Wi0 + (size_t)u * 4096 * 512,
            h0_in, R_N, R_N, Wh0 + (size_t)u * 4096 * 1024,
            bi0 + (size_t)u * 4096, bh0 + (size_t)u * 4096,
            c0, h0_out, R_N);
        // Layer 1: pre1 = h0n @ Wi1[u]^T + h1 @ Wh1[u]^T + biases
        //   h1 input = out slot u; h1 output = out slot u+1.
        lstm_layer<<<grid, 512, 0, stream>>>(
            h0_out, R_N, R_N, Wi1 + (size_t)u * 4096 * 1024,
            out + (size_t)u * R_N, U_N * R_N, R_N, Wh1 + (size_t)u * 4096 * 1024,
            bi1 + (size_t)u * 4096, bh1 + (size_t)u * 4096,
            c1, out + (size_t)(u + 1) * R_N, U_N * R_N);
    }
}

// Round 4
// 1336.078 us; speedup vs baseline: 1.0852x; 1.0852x over previous
//
#include <hip/hip_runtime.h>
#include <hip/hip_bf16.h>

// B=256, I=512, R=1024, L=2, U=11 (step 10's compute is dead; only 10 steps run).
#define B_N 256
#define R_N 1024
#define U_N 11
#define BK 32
#define SP 40    // staging LDS row stride in bf16 elems (BK+8): 80B rows
#define SPP 33   // sPre row stride in floats (32+1): breaks epilogue bank conflicts

typedef __attribute__((ext_vector_type(8))) short bf16x8;
typedef __attribute__((ext_vector_type(4))) float f32x4;

__device__ __forceinline__ float sigmoid_f(float x) {
    return 1.0f / (1.0f + __expf(-x));
}

__device__ __forceinline__ float tanh_f(float x) {
    x = fminf(15.0f, fmaxf(-15.0f, x));
    const float e = __expf(2.0f * x);
    return (e - 1.0f) / (e + 1.0f);
}

__device__ __forceinline__ short bf16_of(float x) {
    union { __hip_bfloat16 h; short s; } u;
    u.h = __float2bfloat16(x);
    return u.s;
}

__device__ __forceinline__ short4 pack4(float4 v) {
    short4 r;
    r.x = bf16_of(v.x); r.y = bf16_of(v.y);
    r.z = bf16_of(v.z); r.w = bf16_of(v.w);
    return r;
}

// One LSTM layer: pre = A1 @ W1^T + A2 @ W2^T + bi + bh -> cell -> h_out, c_state.
//
// TRAFFIC-FIRST tiling (round-3 post-mortem: kernel is HBM-bound on W re-fetch;
// re-fetch factor for W = B/M_tile, for A = 4R/N_tile):
//   M_tile = 128 (batch), N_tile = 32 virtual cols = 8 cols x 4 gates.
//   Grid (R/8=128, B/128=2) = 256 blocks -> W re-fetched only 2x (vs 8x before),
//   and the W-sharing block pair (ids rb, rb+128) maps to the SAME XCD
//   (128 % 8 == 0) -> second read L2-hits. A (2MB unique) is L2-resident.
//
// Block: 512 threads = 8 waves; wave w owns rows [w*16, w*16+16) x all 32 vcols,
// accumulating the FULL virtual K (no K-split, no merge pass).
// K-loop: double-buffered LDS, ONE __syncthreads per chunk (proven in round 3:
// reads of buf b at chunk c drain at sync(c+1); next write of b is at c+2).
__global__ __launch_bounds__(512) void lstm_layer(
    const float* __restrict__ A1, int lda1, int K1, const float* __restrict__ W1,
    const float* __restrict__ A2, int lda2, int K2, const float* __restrict__ W2,
    const float* __restrict__ bi, const float* __restrict__ bh,
    float* __restrict__ c_state,
    float* __restrict__ h_out, int ldh)
{
    // LDS layout:
    //   sA: [buf][128*SP] shorts -> 2 * 10240 B = 20480 B   (offs 0)
    //   sW: [buf][ 32*SP] shorts -> 2 *  2560 B =  5120 B   (offs 20480)
    //   sPre: float[128*SPP] = 16896 B (aliases staging, post-loop only)
    __shared__ __align__(16) char smem_raw[25600];

    const int tid  = threadIdx.x;
    const int lane = tid & 63;
    const int wave = tid >> 6;
    const int ln   = lane & 15;
    const int quad = lane >> 4;
    const int lk   = quad * 8;        // k offset within chunk (bf16 elems)

    const int m_base = blockIdx.y * 128;
    const int rb8    = blockIdx.x * 8;   // 8 columns per gate

    const int Ktot = K1 + K2;
    const int NC   = Ktot / BK;       // 48 (layer0) or 64 (layer1) -- even

    // ---- staging coords (constant per thread)
    // A: 128 rows x 32 k-floats = 1024 float4 segs; 512 threads x 2 rows.
    const int arow = tid >> 3;            // 0..63 (and arow+64)
    const int acol = (tid & 7) * 4;       // 0,4,..,28
    // W: 32 vrows x 8 segs = 256 tasks; threads 0..255.
    const int wrow = tid >> 3;            // 0..31 valid when tid<256
    const int wcol = (tid & 7) * 4;
    const int wgate = wrow >> 3;          // 0..3
    const int wcig  = wrow & 7;           // col within gate

    // Hoisted base pointers (kv is the only per-chunk variable).
    const float* baseA1r0 = A1 + (size_t)(m_base + arow) * lda1 + acol;
    const float* baseA1r1 = A1 + (size_t)(m_base + arow + 64) * lda1 + acol;
    const float* baseA2r0 = A2 + (size_t)(m_base + arow) * lda2 + acol;
    const float* baseA2r1 = A2 + (size_t)(m_base + arow + 64) * lda2 + acol;
    const float* baseW1 = W1 + (size_t)(wgate * R_N + rb8 + wcig) * K1 + wcol;
    const float* baseW2 = W2 + (size_t)(wgate * R_N + rb8 + wcig) * K2 + wcol;

    f32x4 acc[2];
#pragma unroll
    for (int rf = 0; rf < 2; ++rf) {
        f32x4 z = {0.0f, 0.0f, 0.0f, 0.0f};
        acc[rf] = z;
    }

    float4 pA0, pA1, pW;

    // ---- chunk loader: global -> registers (8 lanes cover one 128B row seg)
    auto load_chunk = [&](int c) {
        const int kv = c * BK;
        if (kv < K1) {
            pA0 = *reinterpret_cast<const float4*>(baseA1r0 + kv);
            pA1 = *reinterpret_cast<const float4*>(baseA1r1 + kv);
            if (tid < 256) pW = *reinterpret_cast<const float4*>(baseW1 + kv);
        } else {
            const int kc = kv - K1;
            pA0 = *reinterpret_cast<const float4*>(baseA2r0 + kc);
            pA1 = *reinterpret_cast<const float4*>(baseA2r1 + kc);
            if (tid < 256) pW = *reinterpret_cast<const float4*>(baseW2 + kc);
        }
    };

    // ---- one chunk: store regs -> LDS buf, sync, prefetch c+1, read frags, MFMA
    auto body = [&](int c, int buf) {
        short* sAb = reinterpret_cast<short*>(&smem_raw[(size_t)buf * 10240]);
        short* sWb = reinterpret_cast<short*>(&smem_raw[20480 + (size_t)buf * 2560]);

        *reinterpret_cast<short4*>(&sAb[arow * SP + acol]) = pack4(pA0);
        *reinterpret_cast<short4*>(&sAb[(arow + 64) * SP + acol]) = pack4(pA1);
        if (tid < 256)
            *reinterpret_cast<short4*>(&sWb[wrow * SP + wcol]) = pack4(pW);

        __syncthreads();                      // staging visible; prior buf reads drained

        if (c + 1 < NC) load_chunk(c + 1);    // issue early: overlaps reads+MFMA below

        bf16x8 af, wf0, wf1;
        af  = *reinterpret_cast<const bf16x8*>(&sAb[(wave * 16 + ln) * SP + lk]);
        wf0 = *reinterpret_cast<const bf16x8*>(&sWb[ln * SP + lk]);
        wf1 = *reinterpret_cast<const bf16x8*>(&sWb[(16 + ln) * SP + lk]);

        acc[0] = __builtin_amdgcn_mfma_f32_16x16x32_bf16(af, wf0, acc[0], 0, 0, 0);
        acc[1] = __builtin_amdgcn_mfma_f32_16x16x32_bf16(af, wf1, acc[1], 0, 0, 0);
    };

    load_chunk(0);
#pragma unroll 1
    for (int c = 0; c < NC; c += 2) {
        body(c, 0);
        body(c + 1, 1);
    }

    // ---- epilogue: acc -> sPre (aliases staging; safe after barrier), then cell
    __syncthreads();
    float* sPre = reinterpret_cast<float*>(smem_raw);   // [m*SPP + vcol]

    // C/D layout: vcol = rf*16 + (lane&15), row(m) = wave*16 + quad*4 + t.
#pragma unroll
    for (int rf = 0; rf < 2; ++rf)
#pragma unroll
        for (int t = 0; t < 4; ++t)
            sPre[(wave * 16 + quad * 4 + t) * SPP + rf * 16 + ln] = acc[rf][t];
    __syncthreads();

#pragma unroll
    for (int i = 0; i < 2; ++i) {
        const int ci = tid + i * 512;      // 0..1023 over 128m x 8j
        const int m = ci >> 3;
        const int j = ci & 7;
        const int gm = m_base + m;
        const int gr = rb8 + j;
        const float pI = sPre[m * SPP + 0 * 8 + j] + bi[0 * R_N + gr] + bh[0 * R_N + gr];
        const float pF = sPre[m * SPP + 1 * 8 + j] + bi[1 * R_N + gr] + bh[1 * R_N + gr];
        const float pO = sPre[m * SPP + 2 * 8 + j] + bi[2 * R_N + gr] + bh[2 * R_N + gr];
        const float pG = sPre[m * SPP + 3 * 8 + j] + bi[3 * R_N + gr] + bh[3 * R_N + gr];
        const size_t cidx = (size_t)gm * R_N + gr;
        const float cv = sigmoid_f(pF) * c_state[cidx] + sigmoid_f(pI) * tanh_f(pG);
        c_state[cidx] = cv;
        h_out[(size_t)gm * ldh + gr] = sigmoid_f(pO) * tanh_f(cv);
    }
}

// Unpack init_states_input (B, 4, R) -> h0 ws, c0 ws, out slot 0 (h1), c1 ws.
__global__ __launch_bounds__(256) void init_states(
    const float* __restrict__ st, float* __restrict__ h0,
    float* __restrict__ c0, float* __restrict__ c1, float* __restrict__ out)
{
    const int idx = blockIdx.x * 256 + threadIdx.x;  // 0 .. 256*1024-1
    const int b = idx >> 10;
    const int r = idx & 1023;
    const float* s = st + (size_t)b * 4096;
    h0[idx] = s[r];
    c0[idx] = s[1024 + r];
    out[(size_t)b * (U_N * R_N) + r] = s[2048 + r];
    c1[idx] = s[3072 + r];
}

extern "C" void kernel_launch(void* const* d_in, const int* in_sizes, int n_in,
                              void* d_out, int out_size, void* d_ws, size_t ws_size,
                              hipStream_t stream)
{
    const float* x   = (const float*)d_in[0];
    const float* st  = (const float*)d_in[1];
    const float* Wi0 = (const float*)d_in[2];
    const float* bi0 = (const float*)d_in[3];
    const float* Wh0 = (const float*)d_in[4];
    const float* bh0 = (const float*)d_in[5];
    const float* Wi1 = (const float*)d_in[6];
    const float* bi1 = (const float*)d_in[7];
    const float* Wh1 = (const float*)d_in[8];
    const float* bh1 = (const float*)d_in[9];
    float* out = (float*)d_out;

    float* h0a = (float*)d_ws;
    float* h0b = h0a + B_N * R_N;
    float* c0  = h0b + B_N * R_N;
    float* c1  = c0 + B_N * R_N;

    init_states<<<dim3((B_N * R_N) / 256), 256, 0, stream>>>(st, h0a, c0, c1, out);

    // Grid: (R/8 = 128 col-blocks, B/128 = 2 m-blocks) = 256 blocks.
    // W-sharing pair (rb, rb+128) -> same XCD under default round-robin.
    const dim3 grid(R_N / 8, B_N / 128);
    for (int u = 0; u < 10; ++u) {
        const float* h0_in = (u & 1) ? h0b : h0a;
        float* h0_out      = (u & 1) ? h0a : h0b;
        // Layer 0: pre0 = x @ Wi0[u]^T + h0 @ Wh0[u]^T + biases
        lstm_layer<<<grid, 512, 0, stream>>>(
            x, 512, 512, Wi0 + (size_t)u * 4096 * 512,
            h0_in, R_N, R_N, Wh0 + (size_t)u * 4096 * 1024,
            bi0 + (size_t)u * 4096, bh0 + (size_t)u * 4096,
            c0, h0_out, R_N);
        // Layer 1: pre1 = h0n @ Wi1[u]^T + h1 @ Wh1[u]^T + biases
        //   h1 input = out slot u; h1 output = out slot u+1.
        lstm_layer<<<grid, 512, 0, stream>>>(
            h0_out, R_N, R_N, Wi1 + (size_t)u * 4096 * 1024,
            out + (size_t)u * R_N, U_N * R_N, R_N, Wh1 + (size_t)u * 4096 * 1024,
            bi1 + (size_t)u * 4096, bh1 + (size_t)u * 4096,
            c1, out + (size_t)(u + 1) * R_N, U_N * R_N);
    }
}